// Round 1
// baseline (548.581 us; speedup 1.0000x reference)
//
#include <hip/hip_runtime.h>
#include <stdint.h>

// ---------------- types ----------------
typedef unsigned short ush;
typedef __bf16   bf16x8 __attribute__((ext_vector_type(8)));
typedef float    f32x4  __attribute__((ext_vector_type(4)));
typedef uint32_t u32x4  __attribute__((ext_vector_type(4)));

union U16B { u32x4 u; bf16x8 b; };
union P8   { ush us[8]; u32x4 v; };

__device__ __forceinline__ ush f2bf(float f) {
    union { float f; uint32_t u; } v; v.f = f;
    uint32_t r = v.u + 0x7FFFu + ((v.u >> 16) & 1u);   // RNE
    return (ush)(r >> 16);
}

// problem constants
#define BATCH 32
#define CIN   256
#define OC    256
#define HH    56
#define WW    56
#define HWPX  3136
// ws layout (bytes)
#define XT_BYTES   58720256UL   // 32*8*56*64*32 bf16 elems *2
#define POOL_OFF   58720256UL   // 8192 f32
#define ATT_OFF    58753024UL   // 16384 f32
#define WAGG_OFF   58818560UL   // 32*9*256*256 bf16

// ---------------- kernel 0: zero xT + pooled ----------------
__global__ void k_zero(u32x4* __restrict__ p, long n16) {
    long i = (long)blockIdx.x * 256 + threadIdx.x;
    const long step = (long)gridDim.x * 256;
    u32x4 z = (u32x4)(0u);
    for (; i < n16; i += step) p[i] = z;
}

// ---------------- kernel 1: transpose x -> xT bf16 (swizzled) + pooled sums --
// xT layout: [b][icg32 0..7][row 0..55][padcol 0..63][ic 0..31]
//   padcol p: p=0 and p>=57 are zero (halo); p=1..56 <-> image col p-1
//   within the 32-ic line (4 sub-groups of 8), sub 's' stored at slot s ^ xor(p),
//   xor(p) = (p&3) ^ ((p>>2)&3)
__global__ void k_transpose(const float* __restrict__ x, ush* __restrict__ xT,
                            float* __restrict__ pooled) {
    __shared__ float tile[64][65];
    int blk = blockIdx.x;                 // 32 * 4 * 49
    int b   = blk / 196;
    int rem = blk % 196;
    int icg = rem / 49;                   // 64-ic group
    int pxg = rem % 49;                   // 64-px group
    int t = threadIdx.x;

    // load [64 ic][64 px] coalesced
    {
        int icl  = t >> 2, part = t & 3;
        const float* src = x + (size_t)(b * 256 + icg * 64 + icl) * HWPX + pxg * 64 + part * 16;
        #pragma unroll
        for (int k = 0; k < 4; ++k) {
            f32x4 v = *(const f32x4*)(src + k * 4);
            tile[icl][part * 16 + k * 4 + 0] = v[0];
            tile[icl][part * 16 + k * 4 + 1] = v[1];
            tile[icl][part * 16 + k * 4 + 2] = v[2];
            tile[icl][part * 16 + k * 4 + 3] = v[3];
        }
    }
    __syncthreads();

    // pooled partial sums
    if (t < 64) {
        float s = 0.f;
        #pragma unroll 8
        for (int p = 0; p < 64; ++p) s += tile[t][p];
        atomicAdd(pooled + b * 256 + icg * 64 + t, s);
    }

    // transposed + swizzled bf16 writes
    {
        int pxl = t >> 2, icq = t & 3;
        int px  = pxg * 64 + pxl;
        int row = px / 56;
        int col = px - row * 56;
        int p   = col + 1;
        int xorp = (p & 3) ^ ((p >> 2) & 3);
        int icg32   = icg * 2 + (icq >> 1);
        int subbase = (icq & 1) * 2;
        P8 lo, hi;
        #pragma unroll
        for (int m = 0; m < 8; ++m) {
            lo.us[m] = f2bf(tile[icq * 16 + m][pxl]);
            hi.us[m] = f2bf(tile[icq * 16 + 8 + m][pxl]);
        }
        size_t base = (((size_t)(b * 8 + icg32) * 56 + row) * 64 + p) * 32;
        *(u32x4*)(xT + base + (size_t)((subbase ^ xorp) * 8))       = lo.v;
        *(u32x4*)(xT + base + (size_t)(((subbase + 1) ^ xorp) * 8)) = hi.v;
    }
}

// ---------------- kernel 2: attention (1 block, 512 threads) ----------------
__global__ void k_attn(const float* __restrict__ pooled,
                       const float* __restrict__ fc1_w, const float* __restrict__ fc1_b,
                       const float* __restrict__ ln_g,  const float* __restrict__ ln_b,
                       const float* __restrict__ sp_w,  const float* __restrict__ sp_b,
                       float* __restrict__ att) {
    __shared__ float hs[32][16];
    int t = threadIdx.x;
    {   // h = pooled_mean @ fc1_w.T + fc1_b
        int b = t >> 4, j = t & 15;
        float acc = 0.f;
        for (int c = 0; c < 256; ++c) acc += pooled[b * 256 + c] * fc1_w[j * 256 + c];
        hs[b][j] = fc1_b[j] + acc * (1.0f / 3136.0f);
    }
    __syncthreads();
    if (t < 32) {  // LayerNorm + relu (per batch row of 16)
        float mu = 0.f;
        #pragma unroll
        for (int j = 0; j < 16; ++j) mu += hs[t][j];
        mu *= (1.0f / 16.0f);
        float var = 0.f;
        #pragma unroll
        for (int j = 0; j < 16; ++j) { float d = hs[t][j] - mu; var += d * d; }
        var *= (1.0f / 16.0f);
        float inv = rsqrtf(var + 1e-5f);
        #pragma unroll
        for (int j = 0; j < 16; ++j) {
            float v = (hs[t][j] - mu) * inv * ln_g[j] + ln_b[j];
            hs[t][j] = fmaxf(v, 0.f);
        }
    }
    __syncthreads();
    {   // spatial head + per-mixture L1 norm; thread = (b, m)
        int b = t >> 4, m = t & 15;
        float a[33];
        #pragma unroll 1
        for (int i = 0; i < 33; ++i) {
            int p = m * 33 + i;
            float acc = sp_b[p];
            #pragma unroll
            for (int j = 0; j < 16; ++j) acc += hs[b][j] * sp_w[p * 16 + j];
            a[i] = acc;
        }
        float s = 0.f;
        #pragma unroll
        for (int i = 0; i < 33; ++i) s += fabsf(a[i]);
        float inv = 1.0f / (s + 0.001f);
        #pragma unroll
        for (int c = 0; c < 32; ++c) att[(b * 16 + m) * 32 + c] = a[c] * inv;
    }
}

// ---------------- kernel 3: aggregate weights -> Wagg bf16 [b][tap][oc][ic] --
__global__ void k_agg(const float* __restrict__ cells, const float* __restrict__ att,
                      ush* __restrict__ wagg) {
    __shared__ float at[512];
    int blk = blockIdx.x;                 // 32*64
    int b = blk >> 6, co = blk & 63;
    int t = threadIdx.x;
    for (int i = t; i < 512; i += 256) at[i] = att[b * 512 + i];
    __syncthreads();
    int ci = t & 63, gi = t >> 6;
    float acc[4][9];
    #pragma unroll
    for (int g = 0; g < 4; ++g)
        #pragma unroll
        for (int k = 0; k < 9; ++k) acc[g][k] = 0.f;
    for (int c = 0; c < 32; ++c) {
        float a0 = at[(0 + gi) * 32 + c];
        float a1 = at[(4 + gi) * 32 + c];
        float a2 = at[(8 + gi) * 32 + c];
        float a3 = at[(12 + gi) * 32 + c];
        const float* cp = cells + (size_t)c * 36864 + co * 576 + ci * 9;
        #pragma unroll
        for (int k = 0; k < 9; ++k) {
            float cv = cp[k];
            acc[0][k] += a0 * cv; acc[1][k] += a1 * cv;
            acc[2][k] += a2 * cv; acc[3][k] += a3 * cv;
        }
    }
    #pragma unroll
    for (int g = 0; g < 4; ++g)
        #pragma unroll
        for (int k = 0; k < 9; ++k)
            wagg[((size_t)(b * 9 + k) * 256 + g * 64 + co) * 256 + gi * 64 + ci] = f2bf(acc[g][k]);
}

// ---------------- kernel 4: conv via implicit-GEMM MFMA ----------------
// block: one (b, 64-oc tile, 4-row tile); 4 waves, each 32oc x 112px
__global__ __launch_bounds__(256, 3) void k_conv(const ush* __restrict__ xT,
                                                 const ush* __restrict__ wagg,
                                                 float* __restrict__ out) {
    __shared__ __align__(16) ush xs[2][12288];   // [buf][row6][col64][ic32]

    int tid = threadIdx.x;
    // XCD-bijective swizzle: 14 spatial tiles of one (b,octile) share an XCD
    int wg  = blockIdx.x;                // 1792
    int xcd = wg & 7;
    int kk  = wg >> 3;                   // 0..223
    int gq  = kk / 14;
    int sp  = kk - gq * 14;              // spatial tile 0..13
    int g   = gq * 8 + xcd;              // 0..127
    int b   = g >> 2, octile = g & 3;
    int row0 = sp * 4, oc0 = octile * 64;

    int lane = tid & 63, w = tid >> 6;
    int wm = w >> 1, wn = w & 1;
    int l15 = lane & 15, s4 = lane >> 4;

    // zero both LDS buffers (halo cols + invalid rows stay zero forever)
    {
        u32x4 z = (u32x4)(0u);
        #pragma unroll
        for (int i = 0; i < 12; ++i) ((u32x4*)xs)[tid + i * 256] = z;
    }

    int prow[7], pq[7];
    #pragma unroll
    for (int j = 0; j < 7; ++j) {
        int px = wn * 112 + j * 16 + l15;
        prow[j] = px / 56;
        pq[j]   = px - prow[j] * 56;
    }

    unsigned vmask = 0;
    #pragma unroll
    for (int k = 0; k < 6; ++k) {
        int grow = row0 - 1 + k;
        if (grow >= 0 && grow < 56) vmask |= 1u << k;
    }

    const ush* wb = wagg + (size_t)b * 9 * 65536 + (size_t)(oc0 + wm * 32 + l15) * 256 + s4 * 8;
    const ush* xb = xT + (size_t)b * 8 * 56 * 2048 + (size_t)tid * 8;

    f32x4 acc[2][7];
    #pragma unroll
    for (int mi = 0; mi < 2; ++mi)
        #pragma unroll
        for (int j = 0; j < 7; ++j) acc[mi][j] = (f32x4)(0.f);

    __syncthreads();                      // zero-init visible

    // prologue: stage chunk 0 -> buf 0
    {
        u32x4 ld[6];
        #pragma unroll
        for (int k = 0; k < 6; ++k)
            if (vmask & (1u << k)) ld[k] = *(const u32x4*)(xb + (size_t)(row0 - 1 + k) * 2048);
        #pragma unroll
        for (int k = 0; k < 6; ++k)
            if (vmask & (1u << k)) *(u32x4*)(&xs[0][k * 2048 + tid * 8]) = ld[k];
    }
    __syncthreads();

    int buf = 0;
    for (int chunk = 0; chunk < 8; ++chunk) {
        u32x4 ld[6];
        bool pre = chunk < 7;
        if (pre) {   // issue next-chunk global loads early (hide under MFMA)
            #pragma unroll
            for (int k = 0; k < 6; ++k)
                if (vmask & (1u << k))
                    ld[k] = *(const u32x4*)(xb + (size_t)((chunk + 1) * 56 + row0 - 1 + k) * 2048);
        }
        const ush* wtc = wb + chunk * 32;
        const ush* xsb = xs[buf];
        #pragma unroll
        for (int dy = 0; dy < 3; ++dy) {
            #pragma unroll
            for (int dx = 0; dx < 3; ++dx) {
                const int tap = dy * 3 + dx;
                U16B a0, a1;
                a0.u = *(const u32x4*)(wtc + (size_t)tap * 65536);
                a1.u = *(const u32x4*)(wtc + (size_t)tap * 65536 + 16 * 256);
                #pragma unroll
                for (int j = 0; j < 7; ++j) {
                    int q    = pq[j] + dx;
                    int slot = s4 ^ (q & 3) ^ ((q >> 2) & 3);
                    int off  = ((prow[j] + dy) * 64 + q) * 32 + slot * 8;  // ush units
                    U16B bj; bj.u = *(const u32x4*)(xsb + off);
                    acc[0][j] = __builtin_amdgcn_mfma_f32_16x16x32_bf16(a0.b, bj.b, acc[0][j], 0, 0, 0);
                    acc[1][j] = __builtin_amdgcn_mfma_f32_16x16x32_bf16(a1.b, bj.b, acc[1][j], 0, 0, 0);
                }
            }
        }
        if (pre) {   // late ds_write into the other buffer
            ush* xn = xs[buf ^ 1];
            #pragma unroll
            for (int k = 0; k < 6; ++k)
                if (vmask & (1u << k)) *(u32x4*)(&xn[k * 2048 + tid * 8]) = ld[k];
        }
        __syncthreads();
        buf ^= 1;
    }

    // epilogue: C/D layout col=lane&15 (pixel), row=(lane>>4)*4+reg (oc)
    int pxbase = row0 * 56 + wn * 112;
    #pragma unroll
    for (int mi = 0; mi < 2; ++mi) {
        int oc = oc0 + wm * 32 + mi * 16 + s4 * 4;
        #pragma unroll
        for (int j = 0; j < 7; ++j) {
            int px = pxbase + j * 16 + l15;
            float* o = out + (size_t)(b * 256 + oc) * HWPX + px;
            o[0]        = acc[mi][j][0];
            o[HWPX]     = acc[mi][j][1];
            o[2 * HWPX] = acc[mi][j][2];
            o[3 * HWPX] = acc[mi][j][3];
        }
    }
}

// ---------------- launcher ----------------
extern "C" void kernel_launch(void* const* d_in, const int* in_sizes, int n_in,
                              void* d_out, int out_size, void* d_ws, size_t ws_size,
                              hipStream_t stream) {
    const float* x     = (const float*)d_in[0];
    const float* cells = (const float*)d_in[1];
    const float* fc1_w = (const float*)d_in[2];
    const float* fc1_b = (const float*)d_in[3];
    const float* ln_g  = (const float*)d_in[4];
    const float* ln_b  = (const float*)d_in[5];
    const float* sp_w  = (const float*)d_in[6];
    const float* sp_b  = (const float*)d_in[7];
    float* out = (float*)d_out;

    char* ws = (char*)d_ws;
    ush*   xT     = (ush*)ws;
    float* pooled = (float*)(ws + POOL_OFF);
    float* att    = (float*)(ws + ATT_OFF);
    ush*   wagg   = (ush*)(ws + WAGG_OFF);

    // zero xT + pooled (58,753,024 B = 3,672,064 x 16B)
    k_zero<<<2048, 256, 0, stream>>>((u32x4*)ws, 3672064L);
    k_transpose<<<6272, 256, 0, stream>>>(x, xT, pooled);
    k_attn<<<1, 512, 0, stream>>>(pooled, fc1_w, fc1_b, ln_g, ln_b, sp_w, sp_b, att);
    k_agg<<<2048, 256, 0, stream>>>(cells, att, wagg);
    k_conv<<<1792, 256, 0, stream>>>(xT, wagg, out);
}

// Round 3
// 287.805 us; speedup vs baseline: 1.9061x; 1.9061x over previous
//
#include <hip/hip_runtime.h>
#include <stdint.h>

// ---------------- types ----------------
typedef unsigned short ush;
typedef __bf16   bf16x8 __attribute__((ext_vector_type(8)));
typedef float    f32x4  __attribute__((ext_vector_type(4)));
typedef uint32_t u32x4  __attribute__((ext_vector_type(4)));

union U16B { u32x4 u; bf16x8 b; };
union P8   { ush us[8]; u32x4 v; };

template<int V> struct ICx { static constexpr int value = V; };

__device__ __forceinline__ ush f2bf(float f) {
    union { float f; uint32_t u; } v; v.f = f;
    uint32_t r = v.u + 0x7FFFu + ((v.u >> 16) & 1u);   // RNE
    return (ush)(r >> 16);
}

// problem constants
#define HWPX  3136
// ws layout (bytes)
#define POOL_OFF   58720256UL   // 8192 f32
#define ATT_OFF    58753024UL   // 16384 f32
#define WAGG_OFF   58818560UL   // 32*9*256*256 bf16

// ---------------- kernel 0: zero xT halo cols {0,57} + pooled ----------------
// xT rowline = [b][icg32][row] -> 64 cols x 32 ic x 2B = 4096 B; halo col c at byte c*64
__global__ void k_halo(u32x4* __restrict__ xT16, u32x4* __restrict__ pooled16) {
    int i = blockIdx.x * 256 + threadIdx.x;        // 448 blocks -> 114688
    int rl = i >> 3, s = i & 7;
    u32x4 z = (u32x4)(0u);
    size_t byte = (size_t)rl * 4096 + (s < 4 ? s * 16 : 3648 + (s - 4) * 16);
    xT16[byte >> 4] = z;
    if (blockIdx.x < 8) pooled16[blockIdx.x * 256 + threadIdx.x] = z;  // full 32KB
}

// ---------------- kernel 1: transpose x -> xT bf16 (swizzled) + pooled sums --
// xT layout: [b][icg32 0..7][row 0..55][padcol 0..63][ic 0..31]
//   padcol p: p=0 and p=57 are zero halo; p=1..56 <-> image col p-1; 58..63 dead
//   within the 32-ic line (4 sub-groups of 8), sub 's' stored at slot s ^ xor(p),
//   xor(p) = (p&3) ^ ((p>>2)&3)
__global__ void k_transpose(const float* __restrict__ x, ush* __restrict__ xT,
                            float* __restrict__ pooled) {
    __shared__ float tile[64][65];
    int blk = blockIdx.x;                 // 32 * 4 * 49
    int b   = blk / 196;
    int rem = blk % 196;
    int icg = rem / 49;                   // 64-ic group
    int pxg = rem % 49;                   // 64-px group
    int t = threadIdx.x;

    {
        int icl  = t >> 2, part = t & 3;
        const float* src = x + (size_t)(b * 256 + icg * 64 + icl) * HWPX + pxg * 64 + part * 16;
        #pragma unroll
        for (int k = 0; k < 4; ++k) {
            f32x4 v = *(const f32x4*)(src + k * 4);
            tile[icl][part * 16 + k * 4 + 0] = v[0];
            tile[icl][part * 16 + k * 4 + 1] = v[1];
            tile[icl][part * 16 + k * 4 + 2] = v[2];
            tile[icl][part * 16 + k * 4 + 3] = v[3];
        }
    }
    __syncthreads();

    if (t < 64) {
        float s = 0.f;
        #pragma unroll 8
        for (int p = 0; p < 64; ++p) s += tile[t][p];
        atomicAdd(pooled + b * 256 + icg * 64 + t, s);
    }

    {
        int pxl = t >> 2, icq = t & 3;
        int px  = pxg * 64 + pxl;
        int row = px / 56;
        int col = px - row * 56;
        int p   = col + 1;
        int xorp = (p & 3) ^ ((p >> 2) & 3);
        int icg32   = icg * 2 + (icq >> 1);
        int subbase = (icq & 1) * 2;
        P8 lo, hi;
        #pragma unroll
        for (int m = 0; m < 8; ++m) {
            lo.us[m] = f2bf(tile[icq * 16 + m][pxl]);
            hi.us[m] = f2bf(tile[icq * 16 + 8 + m][pxl]);
        }
        size_t base = (((size_t)(b * 8 + icg32) * 56 + row) * 64 + p) * 32;
        *(u32x4*)(xT + base + (size_t)((subbase ^ xorp) * 8))       = lo.v;
        *(u32x4*)(xT + base + (size_t)(((subbase + 1) ^ xorp) * 8)) = hi.v;
    }
}

// ---------------- kernel 2: attention (1 block, 512 threads) ----------------
__global__ void k_attn(const float* __restrict__ pooled,
                       const float* __restrict__ fc1_w, const float* __restrict__ fc1_b,
                       const float* __restrict__ ln_g,  const float* __restrict__ ln_b,
                       const float* __restrict__ sp_w,  const float* __restrict__ sp_b,
                       float* __restrict__ att) {
    __shared__ float hs[32][16];
    int t = threadIdx.x;
    {
        int b = t >> 4, j = t & 15;
        float acc = 0.f;
        for (int c = 0; c < 256; ++c) acc += pooled[b * 256 + c] * fc1_w[j * 256 + c];
        hs[b][j] = fc1_b[j] + acc * (1.0f / 3136.0f);
    }
    __syncthreads();
    if (t < 32) {
        float mu = 0.f;
        #pragma unroll
        for (int j = 0; j < 16; ++j) mu += hs[t][j];
        mu *= (1.0f / 16.0f);
        float var = 0.f;
        #pragma unroll
        for (int j = 0; j < 16; ++j) { float d = hs[t][j] - mu; var += d * d; }
        var *= (1.0f / 16.0f);
        float inv = rsqrtf(var + 1e-5f);
        #pragma unroll
        for (int j = 0; j < 16; ++j) {
            float v = (hs[t][j] - mu) * inv * ln_g[j] + ln_b[j];
            hs[t][j] = fmaxf(v, 0.f);
        }
    }
    __syncthreads();
    {
        int b = t >> 4, m = t & 15;
        float a[33];
        #pragma unroll 1
        for (int i = 0; i < 33; ++i) {
            int p = m * 33 + i;
            float acc = sp_b[p];
            #pragma unroll
            for (int j = 0; j < 16; ++j) acc += hs[b][j] * sp_w[p * 16 + j];
            a[i] = acc;
        }
        float s = 0.f;
        #pragma unroll
        for (int i = 0; i < 33; ++i) s += fabsf(a[i]);
        float inv = 1.0f / (s + 0.001f);
        #pragma unroll
        for (int c = 0; c < 32; ++c) att[(b * 16 + m) * 32 + c] = a[c] * inv;
    }
}

// ---------------- kernel 3: aggregate weights -> Wagg bf16 [b][tap][oc][ic] --
__global__ void k_agg(const float* __restrict__ cells, const float* __restrict__ att,
                      ush* __restrict__ wagg) {
    __shared__ float at[512];
    int blk = blockIdx.x;                 // 32*64
    int b = blk >> 6, co = blk & 63;
    int t = threadIdx.x;
    for (int i = t; i < 512; i += 256) at[i] = att[b * 512 + i];
    __syncthreads();
    int ci = t & 63, gi = t >> 6;
    float acc[4][9];
    #pragma unroll
    for (int g = 0; g < 4; ++g)
        #pragma unroll
        for (int k = 0; k < 9; ++k) acc[g][k] = 0.f;
    for (int c = 0; c < 32; ++c) {
        float a0 = at[(0 + gi) * 32 + c];
        float a1 = at[(4 + gi) * 32 + c];
        float a2 = at[(8 + gi) * 32 + c];
        float a3 = at[(12 + gi) * 32 + c];
        const float* cp = cells + (size_t)c * 36864 + co * 576 + ci * 9;
        #pragma unroll
        for (int k = 0; k < 9; ++k) {
            float cv = cp[k];
            acc[0][k] += a0 * cv; acc[1][k] += a1 * cv;
            acc[2][k] += a2 * cv; acc[3][k] += a3 * cv;
        }
    }
    #pragma unroll
    for (int g = 0; g < 4; ++g)
        #pragma unroll
        for (int k = 0; k < 9; ++k)
            wagg[((size_t)(b * 9 + k) * 256 + g * 64 + co) * 256 + gi * 64 + ci] = f2bf(acc[g][k]);
}

// ---------------- kernel 4: conv via implicit-GEMM MFMA ----------------
// A = x pixels (M), B = weights (N=oc) -> D rows are 4 consecutive px per lane
// block: one (b, 64-oc tile, 4-row tile); 4 waves, each 32oc x 112px
__global__ __launch_bounds__(256, 3) void k_conv(const ush* __restrict__ xT,
                                                 const ush* __restrict__ wagg,
                                                 float* __restrict__ out) {
    __shared__ __align__(16) ush xs[2][12288];   // [buf][row6][col64][ic32]

    int tid = threadIdx.x;
    // XCD-grouped: 14 spatial tiles of one (b,octile) share an XCD
    int wg  = blockIdx.x;                // 1792
    int xcd = wg & 7;
    int kk  = wg >> 3;                   // 0..223
    int gq  = kk / 14;
    int sp  = kk - gq * 14;              // spatial tile 0..13
    int g   = gq * 8 + xcd;              // 0..127
    int b   = g >> 2, octile = g & 3;
    int row0 = sp * 4, oc0 = octile * 64;

    int lane = tid & 63, w = tid >> 6;
    int wm = w >> 1, wn = w & 1;
    int l15 = lane & 15, s4 = lane >> 4;

    {   // zero both LDS buffers (halo rows stay zero forever)
        u32x4 z = (u32x4)(0u);
        #pragma unroll
        for (int i = 0; i < 12; ++i) ((u32x4*)xs)[tid + i * 256] = z;
    }

    int prow[7], pq[7];
    #pragma unroll
    for (int j = 0; j < 7; ++j) {
        int px = wn * 112 + j * 16 + l15;
        prow[j] = px / 56;
        pq[j]   = px - prow[j] * 56;
    }

    unsigned vmask = 0;
    #pragma unroll
    for (int k = 0; k < 6; ++k) {
        int grow = row0 - 1 + k;
        if (grow >= 0 && grow < 56) vmask |= 1u << k;
    }

    // weight base: B-frag lane l needs W[oc=l15][ic=s4*8 ..+8] contiguous
    const ush* wb = wagg + (size_t)b * 9 * 65536 + (size_t)(oc0 + wm * 32 + l15) * 256 + s4 * 8;
    const ush* xb = xT + (size_t)b * 8 * 56 * 2048 + (size_t)tid * 8;

    f32x4 acc[2][7];
    #pragma unroll
    for (int mi = 0; mi < 2; ++mi)
        #pragma unroll
        for (int j = 0; j < 7; ++j) acc[mi][j] = (f32x4)(0.f);

    // weight pipeline stages hold global steps k and k+1 (k = chunk*9+tap);
    // stage index = (chunk + tap) & 1  (9 taps/chunk is ODD -> parity flips per chunk)
    U16B wp0a, wp0b, wp1a, wp1b;
    wp0a.u = *(const u32x4*)(wb);                     // (c0,t0) -> stage 0
    wp0b.u = *(const u32x4*)(wb + 4096);
    wp1a.u = *(const u32x4*)(wb + 65536);             // (c0,t1) -> stage 1
    wp1b.u = *(const u32x4*)(wb + 65536 + 4096);

    __syncthreads();                      // LDS zero visible

    // prologue: stage x chunk 0 -> buf 0
    {
        u32x4 ld[6];
        #pragma unroll
        for (int k = 0; k < 6; ++k)
            if (vmask & (1u << k)) ld[k] = *(const u32x4*)(xb + (size_t)(row0 - 1 + k) * 2048);
        #pragma unroll
        for (int k = 0; k < 6; ++k)
            if (vmask & (1u << k)) *(u32x4*)(&xs[0][k * 2048 + tid * 8]) = ld[k];
    }
    __syncthreads();

    auto chunk_body = [&](auto parc, int chunk) {
        constexpr int PAR = decltype(parc)::value;    // == chunk & 1, compile-time
        u32x4 ld[6];
        bool pre = chunk < 7;
        if (pre) {   // next x-tile global->reg (hidden under MFMA)
            #pragma unroll
            for (int k = 0; k < 6; ++k)
                if (vmask & (1u << k))
                    ld[k] = *(const u32x4*)(xb + (size_t)((chunk + 1) * 56 + row0 - 1 + k) * 2048);
        }
        const ush* xsb = xs[PAR];
        #pragma unroll
        for (int tap = 0; tap < 9; ++tap) {
            const int dy = tap / 3, dx = tap % 3;
            U16B a0, a1;
            if ((PAR + tap) & 1) { a0 = wp1a; a1 = wp1b; } else { a0 = wp0a; a1 = wp0b; }
            // prefetch step k+2 into the stage just consumed
            {
                int nt = tap + 2, nc = chunk;
                if (nt >= 9) { nt -= 9; ++nc; }
                if (nc < 8) {
                    const ush* wnx = wb + (size_t)nt * 65536 + (size_t)nc * 32;
                    if ((PAR + tap) & 1) {
                        wp1a.u = *(const u32x4*)(wnx);
                        wp1b.u = *(const u32x4*)(wnx + 4096);
                    } else {
                        wp0a.u = *(const u32x4*)(wnx);
                        wp0b.u = *(const u32x4*)(wnx + 4096);
                    }
                }
            }
            #pragma unroll
            for (int j = 0; j < 7; ++j) {
                int q    = pq[j] + dx;
                int slot = s4 ^ (q & 3) ^ ((q >> 2) & 3);
                int off  = ((prow[j] + dy) * 64 + q) * 32 + slot * 8;  // ush units
                U16B bj; bj.u = *(const u32x4*)(xsb + off);
                acc[0][j] = __builtin_amdgcn_mfma_f32_16x16x32_bf16(bj.b, a0.b, acc[0][j], 0, 0, 0);
                acc[1][j] = __builtin_amdgcn_mfma_f32_16x16x32_bf16(bj.b, a1.b, acc[1][j], 0, 0, 0);
            }
        }
        if (pre) {
            ush* xn = xs[PAR ^ 1];
            #pragma unroll
            for (int k = 0; k < 6; ++k)
                if (vmask & (1u << k)) *(u32x4*)(&xn[k * 2048 + tid * 8]) = ld[k];
        }
        __syncthreads();
    };

    for (int c2 = 0; c2 < 8; c2 += 2) {
        chunk_body(ICx<0>{}, c2);
        chunk_body(ICx<1>{}, c2 + 1);
    }

    // epilogue: D row = px (4 consecutive per lane), col = oc = lane&15 of frag
    int pxbase = row0 * 56 + wn * 112 + s4 * 4;
    #pragma unroll
    for (int mi = 0; mi < 2; ++mi) {
        int oc = oc0 + wm * 32 + mi * 16 + l15;
        float* o = out + (size_t)(b * 256 + oc) * HWPX + pxbase;
        #pragma unroll
        for (int j = 0; j < 7; ++j)
            *(f32x4*)(o + j * 16) = acc[mi][j];
    }
}

// ---------------- launcher ----------------
extern "C" void kernel_launch(void* const* d_in, const int* in_sizes, int n_in,
                              void* d_out, int out_size, void* d_ws, size_t ws_size,
                              hipStream_t stream) {
    const float* x     = (const float*)d_in[0];
    const float* cells = (const float*)d_in[1];
    const float* fc1_w = (const float*)d_in[2];
    const float* fc1_b = (const float*)d_in[3];
    const float* ln_g  = (const float*)d_in[4];
    const float* ln_b  = (const float*)d_in[5];
    const float* sp_w  = (const float*)d_in[6];
    const float* sp_b  = (const float*)d_in[7];
    float* out = (float*)d_out;

    char* ws = (char*)d_ws;
    ush*   xT     = (ush*)ws;
    float* pooled = (float*)(ws + POOL_OFF);
    float* att    = (float*)(ws + ATT_OFF);
    ush*   wagg   = (ush*)(ws + WAGG_OFF);

    k_halo<<<448, 256, 0, stream>>>((u32x4*)ws, (u32x4*)pooled);
    k_transpose<<<6272, 256, 0, stream>>>(x, xT, pooled);
    k_attn<<<1, 512, 0, stream>>>(pooled, fc1_w, fc1_b, ln_g, ln_b, sp_w, sp_b, att);
    k_agg<<<2048, 256, 0, stream>>>(cells, att, wagg);
    k_conv<<<1792, 256, 0, stream>>>(xT, wagg, out);
}

// Round 4
// 275.761 us; speedup vs baseline: 1.9893x; 1.0437x over previous
//
#include <hip/hip_runtime.h>
#include <stdint.h>

// ---------------- types ----------------
typedef unsigned short ush;
typedef __bf16   bf16x8 __attribute__((ext_vector_type(8)));
typedef float    f32x4  __attribute__((ext_vector_type(4)));
typedef uint32_t u32x4  __attribute__((ext_vector_type(4)));

union U16B { u32x4 u; bf16x8 b; };
union P8   { ush us[8]; u32x4 v; };

template<int V> struct ICx { static constexpr int value = V; };

__device__ __forceinline__ ush f2bf(float f) {
    union { float f; uint32_t u; } v; v.f = f;
    uint32_t r = v.u + 0x7FFFu + ((v.u >> 16) & 1u);   // RNE
    return (ush)(r >> 16);
}

__device__ __forceinline__ void gl_lds16(const ush* g, ush* l) {
    __builtin_amdgcn_global_load_lds(
        (const __attribute__((address_space(1))) uint32_t*)g,
        (__attribute__((address_space(3))) uint32_t*)l, 16, 0, 0);
}

// problem constants
#define HWPX  3136
// ws layout (bytes)
#define POOL_OFF   58720256UL   // 8192 f32
#define ATT_OFF    58753024UL   // 16384 f32
#define WAGG_OFF   58818560UL   // 32*9*256*256 bf16

// ---------------- kernel 0: zero xT halo cols {0,57} + pooled ----------------
// xT rowline = [b][icg32][row] -> 64 cols x 32 ic x 2B = 4096 B; halo col c at byte c*64
__global__ void k_halo(u32x4* __restrict__ xT16, u32x4* __restrict__ pooled16) {
    int i = blockIdx.x * 256 + threadIdx.x;        // 448 blocks -> 114688
    int rl = i >> 3, s = i & 7;
    u32x4 z = (u32x4)(0u);
    size_t byte = (size_t)rl * 4096 + (s < 4 ? s * 16 : 3648 + (s - 4) * 16);
    xT16[byte >> 4] = z;
    if (blockIdx.x < 8) pooled16[blockIdx.x * 256 + threadIdx.x] = z;  // full 32KB
}

// ---------------- kernel 1: transpose x -> xT bf16 (swizzled) + pooled sums --
// xT layout: [b][icg32 0..7][row 0..55][padcol 0..63][ic 0..31]
//   padcol p: p=0 and p=57 are zero halo; p=1..56 <-> image col p-1; 58..63 dead
//   within the 32-ic line (4 sub-groups of 8), sub 's' stored at slot s ^ xor(p),
//   xor(p) = (p>>1)&3  -> (p&1, slot) == p mod 8: injective on EVERY 8-col window
__global__ void k_transpose(const float* __restrict__ x, ush* __restrict__ xT,
                            float* __restrict__ pooled) {
    __shared__ float tile[64][65];
    int blk = blockIdx.x;                 // 32 * 4 * 49
    int b   = blk / 196;
    int rem = blk % 196;
    int icg = rem / 49;                   // 64-ic group
    int pxg = rem % 49;                   // 64-px group
    int t = threadIdx.x;

    {
        int icl  = t >> 2, part = t & 3;
        const float* src = x + (size_t)(b * 256 + icg * 64 + icl) * HWPX + pxg * 64 + part * 16;
        #pragma unroll
        for (int k = 0; k < 4; ++k) {
            f32x4 v = *(const f32x4*)(src + k * 4);
            tile[icl][part * 16 + k * 4 + 0] = v[0];
            tile[icl][part * 16 + k * 4 + 1] = v[1];
            tile[icl][part * 16 + k * 4 + 2] = v[2];
            tile[icl][part * 16 + k * 4 + 3] = v[3];
        }
    }
    __syncthreads();

    if (t < 64) {
        float s = 0.f;
        #pragma unroll 8
        for (int p = 0; p < 64; ++p) s += tile[t][p];
        atomicAdd(pooled + b * 256 + icg * 64 + t, s);
    }

    {
        int pxl = t >> 2, icq = t & 3;
        int px  = pxg * 64 + pxl;
        int row = px / 56;
        int col = px - row * 56;
        int p   = col + 1;
        int xorp = (p >> 1) & 3;
        int icg32   = icg * 2 + (icq >> 1);
        int subbase = (icq & 1) * 2;
        P8 lo, hi;
        #pragma unroll
        for (int m = 0; m < 8; ++m) {
            lo.us[m] = f2bf(tile[icq * 16 + m][pxl]);
            hi.us[m] = f2bf(tile[icq * 16 + 8 + m][pxl]);
        }
        size_t base = (((size_t)(b * 8 + icg32) * 56 + row) * 64 + p) * 32;
        *(u32x4*)(xT + base + (size_t)((subbase ^ xorp) * 8))       = lo.v;
        *(u32x4*)(xT + base + (size_t)(((subbase + 1) ^ xorp) * 8)) = hi.v;
    }
}

// ---------------- kernel 2: attention (1 block, 512 threads) ----------------
__global__ void k_attn(const float* __restrict__ pooled,
                       const float* __restrict__ fc1_w, const float* __restrict__ fc1_b,
                       const float* __restrict__ ln_g,  const float* __restrict__ ln_b,
                       const float* __restrict__ sp_w,  const float* __restrict__ sp_b,
                       float* __restrict__ att) {
    __shared__ float hs[32][16];
    int t = threadIdx.x;
    {
        int b = t >> 4, j = t & 15;
        float acc = 0.f;
        for (int c = 0; c < 256; ++c) acc += pooled[b * 256 + c] * fc1_w[j * 256 + c];
        hs[b][j] = fc1_b[j] + acc * (1.0f / 3136.0f);
    }
    __syncthreads();
    if (t < 32) {
        float mu = 0.f;
        #pragma unroll
        for (int j = 0; j < 16; ++j) mu += hs[t][j];
        mu *= (1.0f / 16.0f);
        float var = 0.f;
        #pragma unroll
        for (int j = 0; j < 16; ++j) { float d = hs[t][j] - mu; var += d * d; }
        var *= (1.0f / 16.0f);
        float inv = rsqrtf(var + 1e-5f);
        #pragma unroll
        for (int j = 0; j < 16; ++j) {
            float v = (hs[t][j] - mu) * inv * ln_g[j] + ln_b[j];
            hs[t][j] = fmaxf(v, 0.f);
        }
    }
    __syncthreads();
    {
        int b = t >> 4, m = t & 15;
        float a[33];
        #pragma unroll 1
        for (int i = 0; i < 33; ++i) {
            int p = m * 33 + i;
            float acc = sp_b[p];
            #pragma unroll
            for (int j = 0; j < 16; ++j) acc += hs[b][j] * sp_w[p * 16 + j];
            a[i] = acc;
        }
        float s = 0.f;
        #pragma unroll
        for (int i = 0; i < 33; ++i) s += fabsf(a[i]);
        float inv = 1.0f / (s + 0.001f);
        #pragma unroll
        for (int c = 0; c < 32; ++c) att[(b * 16 + m) * 32 + c] = a[c] * inv;
    }
}

// ---------------- kernel 3: aggregate weights -> Wagg bf16 [b][tap][oc][ic] --
__global__ void k_agg(const float* __restrict__ cells, const float* __restrict__ att,
                      ush* __restrict__ wagg) {
    __shared__ float at[512];
    int blk = blockIdx.x;                 // 32*64
    int b = blk >> 6, co = blk & 63;
    int t = threadIdx.x;
    for (int i = t; i < 512; i += 256) at[i] = att[b * 512 + i];
    __syncthreads();
    int ci = t & 63, gi = t >> 6;
    float acc[4][9];
    #pragma unroll
    for (int g = 0; g < 4; ++g)
        #pragma unroll
        for (int k = 0; k < 9; ++k) acc[g][k] = 0.f;
    for (int c = 0; c < 32; ++c) {
        float a0 = at[(0 + gi) * 32 + c];
        float a1 = at[(4 + gi) * 32 + c];
        float a2 = at[(8 + gi) * 32 + c];
        float a3 = at[(12 + gi) * 32 + c];
        const float* cp = cells + (size_t)c * 36864 + co * 576 + ci * 9;
        #pragma unroll
        for (int k = 0; k < 9; ++k) {
            float cv = cp[k];
            acc[0][k] += a0 * cv; acc[1][k] += a1 * cv;
            acc[2][k] += a2 * cv; acc[3][k] += a3 * cv;
        }
    }
    #pragma unroll
    for (int g = 0; g < 4; ++g)
        #pragma unroll
        for (int k = 0; k < 9; ++k)
            wagg[((size_t)(b * 9 + k) * 256 + g * 64 + co) * 256 + gi * 64 + ci] = f2bf(acc[g][k]);
}

// ---------------- kernel 4: conv via implicit-GEMM MFMA ----------------
// A = x pixels (M), B = weights (N=oc); wave = 112 px x 64 oc (7 x-frags x 4 w-frags)
// block: (b, 128-oc tile, 4-row tile); 4 waves = 2 px-halves x 2 oc-halves
__global__ __launch_bounds__(256, 2) void k_conv(const ush* __restrict__ xT,
                                                 const ush* __restrict__ wagg,
                                                 float* __restrict__ out) {
    __shared__ __align__(16) ush xs[2][12288];   // [buf][row6][col64][ic32]

    int tid = threadIdx.x;
    // XCD-grouped: 14 spatial tiles of one (b,octile) land on one XCD
    int wg  = blockIdx.x;                // 896
    int xcd = wg & 7;
    int kk  = wg >> 3;                   // 0..111
    int gq  = kk / 14;                   // 0..7
    int sp  = kk - gq * 14;              // spatial tile 0..13
    int g   = gq * 8 + xcd;              // 0..63
    int b   = g >> 1, octile = g & 1;
    int row0 = sp * 4, oc0 = octile * 128;

    int lane = tid & 63, w = tid >> 6;
    int wm = w >> 1, wn = w & 1;         // wm: oc half (64), wn: px half (112)
    int l15 = lane & 15, s4 = lane >> 4;

    {   // zero both LDS buffers (invalid rows stay zero forever)
        u32x4 z = (u32x4)(0u);
        #pragma unroll
        for (int i = 0; i < 12; ++i) ((u32x4*)xs)[tid + i * 256] = z;
    }

    int prow[7], pq[7];
    #pragma unroll
    for (int j = 0; j < 7; ++j) {
        int px = wn * 112 + j * 16 + l15;
        prow[j] = px / 56;
        pq[j]   = px - prow[j] * 56;
    }

    unsigned vmask = 0;
    #pragma unroll
    for (int k = 0; k < 6; ++k) {
        int grow = row0 - 1 + k;
        if (grow >= 0 && grow < 56) vmask |= 1u << k;
    }

    // weight base: frag mi -> oc = oc0 + wm*64 + mi*16 + l15, ic = s4*8..+8
    const ush* wb = wagg + (size_t)b * 9 * 65536 + (size_t)(oc0 + wm * 64 + l15) * 256 + s4 * 8;
    const ush* xb = xT + (size_t)b * 8 * 56 * 2048 + (size_t)tid * 8;   // per-lane
    ush* lq = &xs[0][0];                 // base; buffer offset added statically

    f32x4 acc[4][7];
    #pragma unroll
    for (int mi = 0; mi < 4; ++mi)
        #pragma unroll
        for (int j = 0; j < 7; ++j) acc[mi][j] = (f32x4)(0.f);

    // weight pipeline: stage = (chunk + tap) & 1 (9 taps/chunk is odd)
    U16B wpa[2][4];
    #pragma unroll
    for (int mi = 0; mi < 4; ++mi) {
        wpa[0][mi].u = *(const u32x4*)(wb + mi * 4096);           // (c0,t0)
        wpa[1][mi].u = *(const u32x4*)(wb + 65536 + mi * 4096);   // (c0,t1)
    }

    __syncthreads();                      // LDS zero visible before DMA

    // prologue: DMA x chunk 0 -> buf 0 (dest = wave-uniform base + lane*16B)
    #pragma unroll
    for (int k = 0; k < 6; ++k)
        if (vmask & (1u << k))
            gl_lds16(xb + (size_t)(row0 - 1 + k) * 2048, lq + k * 2048 + w * 512);
    __syncthreads();

    auto chunk_body = [&](auto parc, int chunk) {
        constexpr int PAR = decltype(parc)::value;    // == chunk & 1
        if (chunk < 7) {   // DMA next chunk into other buffer (drained by barrier)
            #pragma unroll
            for (int k = 0; k < 6; ++k)
                if (vmask & (1u << k))
                    gl_lds16(xb + (size_t)((chunk + 1) * 56 + row0 - 1 + k) * 2048,
                             lq + (PAR ^ 1) * 12288 + k * 2048 + w * 512);
        }
        const ush* xsb = xs[PAR];
        #pragma unroll
        for (int tap = 0; tap < 9; ++tap) {
            const int dy = tap / 3, dx = tap % 3;
            U16B a0, a1, a2, a3;
            if ((PAR + tap) & 1) { a0 = wpa[1][0]; a1 = wpa[1][1]; a2 = wpa[1][2]; a3 = wpa[1][3]; }
            else                 { a0 = wpa[0][0]; a1 = wpa[0][1]; a2 = wpa[0][2]; a3 = wpa[0][3]; }
            {   // prefetch step k+2 into the stage just consumed
                int nt = tap + 2, nc = chunk;
                if (nt >= 9) { nt -= 9; ++nc; }
                if (nc < 8) {
                    const ush* wnx = wb + (size_t)nt * 65536 + (size_t)nc * 32;
                    if ((PAR + tap) & 1) {
                        #pragma unroll
                        for (int mi = 0; mi < 4; ++mi) wpa[1][mi].u = *(const u32x4*)(wnx + mi * 4096);
                    } else {
                        #pragma unroll
                        for (int mi = 0; mi < 4; ++mi) wpa[0][mi].u = *(const u32x4*)(wnx + mi * 4096);
                    }
                }
            }
            #pragma unroll
            for (int j = 0; j < 7; ++j) {
                int q    = pq[j] + dx;
                int slot = s4 ^ ((q >> 1) & 3);
                int off  = ((prow[j] + dy) * 64 + q) * 32 + slot * 8;  // ush units
                U16B bj; bj.u = *(const u32x4*)(xsb + off);
                acc[0][j] = __builtin_amdgcn_mfma_f32_16x16x32_bf16(bj.b, a0.b, acc[0][j], 0, 0, 0);
                acc[1][j] = __builtin_amdgcn_mfma_f32_16x16x32_bf16(bj.b, a1.b, acc[1][j], 0, 0, 0);
                acc[2][j] = __builtin_amdgcn_mfma_f32_16x16x32_bf16(bj.b, a2.b, acc[2][j], 0, 0, 0);
                acc[3][j] = __builtin_amdgcn_mfma_f32_16x16x32_bf16(bj.b, a3.b, acc[3][j], 0, 0, 0);
            }
        }
        __syncthreads();   // drains DMA (vmcnt) + orders buffer swap
    };

    for (int c2 = 0; c2 < 8; c2 += 2) {
        chunk_body(ICx<0>{}, c2);
        chunk_body(ICx<1>{}, c2 + 1);
    }

    // epilogue: D row = px (4 consecutive per lane via s4), col = oc (l15)
    int pxbase = row0 * 56 + wn * 112 + s4 * 4;
    #pragma unroll
    for (int mi = 0; mi < 4; ++mi) {
        int oc = oc0 + wm * 64 + mi * 16 + l15;
        float* o = out + (size_t)(b * 256 + oc) * HWPX + pxbase;
        #pragma unroll
        for (int j = 0; j < 7; ++j)
            *(f32x4*)(o + j * 16) = acc[mi][j];
    }
}

// ---------------- launcher ----------------
extern "C" void kernel_launch(void* const* d_in, const int* in_sizes, int n_in,
                              void* d_out, int out_size, void* d_ws, size_t ws_size,
                              hipStream_t stream) {
    const float* x     = (const float*)d_in[0];
    const float* cells = (const float*)d_in[1];
    const float* fc1_w = (const float*)d_in[2];
    const float* fc1_b = (const float*)d_in[3];
    const float* ln_g  = (const float*)d_in[4];
    const float* ln_b  = (const float*)d_in[5];
    const float* sp_w  = (const float*)d_in[6];
    const float* sp_b  = (const float*)d_in[7];
    float* out = (float*)d_out;

    char* ws = (char*)d_ws;
    ush*   xT     = (ush*)ws;
    float* pooled = (float*)(ws + POOL_OFF);
    float* att    = (float*)(ws + ATT_OFF);
    ush*   wagg   = (ush*)(ws + WAGG_OFF);

    k_halo<<<448, 256, 0, stream>>>((u32x4*)ws, (u32x4*)pooled);
    k_transpose<<<6272, 256, 0, stream>>>(x, xT, pooled);
    k_attn<<<1, 512, 0, stream>>>(pooled, fc1_w, fc1_b, ln_g, ln_b, sp_w, sp_b, att);
    k_agg<<<2048, 256, 0, stream>>>(cells, att, wagg);
    k_conv<<<896, 256, 0, stream>>>(xT, wagg, out);
}

// Round 5
// 272.407 us; speedup vs baseline: 2.0138x; 1.0123x over previous
//
#include <hip/hip_runtime.h>
#include <stdint.h>

// ---------------- types ----------------
typedef unsigned short ush;
typedef __bf16   bf16x8 __attribute__((ext_vector_type(8)));
typedef float    f32x4  __attribute__((ext_vector_type(4)));
typedef uint32_t u32x4  __attribute__((ext_vector_type(4)));

union U16B { u32x4 u; bf16x8 b; };
union P8   { ush us[8]; u32x4 v; };

template<int V> struct ICx { static constexpr int value = V; };

__device__ __forceinline__ ush f2bf(float f) {
    union { float f; uint32_t u; } v; v.f = f;
    uint32_t r = v.u + 0x7FFFu + ((v.u >> 16) & 1u);   // RNE
    return (ush)(r >> 16);
}

__device__ __forceinline__ void gl_lds16(const ush* g, ush* l) {
    __builtin_amdgcn_global_load_lds(
        (const __attribute__((address_space(1))) uint32_t*)g,
        (__attribute__((address_space(3))) uint32_t*)l, 16, 0, 0);
}

// problem constants
#define HWPX  3136
// ws layout (bytes)
#define POOL_OFF   58720256UL   // 8192 f32
#define ATT_OFF    58753024UL   // 16384 f32
#define WAGG_OFF   58818560UL   // 32*9*256*256 bf16

// ---------------- kernel 0: zero xT halo cols {0,57} + pooled ----------------
// xT rowline = [b][icg32][row] -> 64 cols x 32 ic x 2B = 4096 B; halo col c at byte c*64
__global__ void k_halo(u32x4* __restrict__ xT16, u32x4* __restrict__ pooled16) {
    int i = blockIdx.x * 256 + threadIdx.x;        // 448 blocks -> 114688
    int rl = i >> 3, s = i & 7;
    u32x4 z = (u32x4)(0u);
    size_t byte = (size_t)rl * 4096 + (s < 4 ? s * 16 : 3648 + (s - 4) * 16);
    xT16[byte >> 4] = z;
    if (blockIdx.x < 8) pooled16[blockIdx.x * 256 + threadIdx.x] = z;  // full 32KB
}

// ---------------- kernel 1: transpose x -> xT bf16 (swizzled) + pooled sums --
// xT layout: [b][icg32 0..7][row 0..55][padcol 0..63][ic 0..31]
//   padcol p: p=0 and p=57 are zero halo; p=1..56 <-> image col p-1; 58..63 dead
//   within the 32-ic line (4 sub-groups of 8), sub 's' stored at slot s ^ xor(p),
//   xor(p) = (p>>1)&3  -> (p&1, slot) == p mod 8: injective on EVERY 8-col window
__global__ void k_transpose(const float* __restrict__ x, ush* __restrict__ xT,
                            float* __restrict__ pooled) {
    __shared__ float tile[64][65];
    int blk = blockIdx.x;                 // 32 * 4 * 49
    int b   = blk / 196;
    int rem = blk % 196;
    int icg = rem / 49;                   // 64-ic group
    int pxg = rem % 49;                   // 64-px group
    int t = threadIdx.x;

    {
        int icl  = t >> 2, part = t & 3;
        const float* src = x + (size_t)(b * 256 + icg * 64 + icl) * HWPX + pxg * 64 + part * 16;
        #pragma unroll
        for (int k = 0; k < 4; ++k) {
            f32x4 v = *(const f32x4*)(src + k * 4);
            tile[icl][part * 16 + k * 4 + 0] = v[0];
            tile[icl][part * 16 + k * 4 + 1] = v[1];
            tile[icl][part * 16 + k * 4 + 2] = v[2];
            tile[icl][part * 16 + k * 4 + 3] = v[3];
        }
    }
    __syncthreads();

    if (t < 64) {
        float s = 0.f;
        #pragma unroll 8
        for (int p = 0; p < 64; ++p) s += tile[t][p];
        atomicAdd(pooled + b * 256 + icg * 64 + t, s);
    }

    {
        int pxl = t >> 2, icq = t & 3;
        int px  = pxg * 64 + pxl;
        int row = px / 56;
        int col = px - row * 56;
        int p   = col + 1;
        int xorp = (p >> 1) & 3;
        int icg32   = icg * 2 + (icq >> 1);
        int subbase = (icq & 1) * 2;
        P8 lo, hi;
        #pragma unroll
        for (int m = 0; m < 8; ++m) {
            lo.us[m] = f2bf(tile[icq * 16 + m][pxl]);
            hi.us[m] = f2bf(tile[icq * 16 + 8 + m][pxl]);
        }
        size_t base = (((size_t)(b * 8 + icg32) * 56 + row) * 64 + p) * 32;
        *(u32x4*)(xT + base + (size_t)((subbase ^ xorp) * 8))       = lo.v;
        *(u32x4*)(xT + base + (size_t)(((subbase + 1) ^ xorp) * 8)) = hi.v;
    }
}

// ---------------- kernel 2: attention (1 block, 512 threads) ----------------
__global__ void k_attn(const float* __restrict__ pooled,
                       const float* __restrict__ fc1_w, const float* __restrict__ fc1_b,
                       const float* __restrict__ ln_g,  const float* __restrict__ ln_b,
                       const float* __restrict__ sp_w,  const float* __restrict__ sp_b,
                       float* __restrict__ att) {
    __shared__ float hs[32][16];
    int t = threadIdx.x;
    {
        int b = t >> 4, j = t & 15;
        float acc = 0.f;
        for (int c = 0; c < 256; ++c) acc += pooled[b * 256 + c] * fc1_w[j * 256 + c];
        hs[b][j] = fc1_b[j] + acc * (1.0f / 3136.0f);
    }
    __syncthreads();
    if (t < 32) {
        float mu = 0.f;
        #pragma unroll
        for (int j = 0; j < 16; ++j) mu += hs[t][j];
        mu *= (1.0f / 16.0f);
        float var = 0.f;
        #pragma unroll
        for (int j = 0; j < 16; ++j) { float d = hs[t][j] - mu; var += d * d; }
        var *= (1.0f / 16.0f);
        float inv = rsqrtf(var + 1e-5f);
        #pragma unroll
        for (int j = 0; j < 16; ++j) {
            float v = (hs[t][j] - mu) * inv * ln_g[j] + ln_b[j];
            hs[t][j] = fmaxf(v, 0.f);
        }
    }
    __syncthreads();
    {
        int b = t >> 4, m = t & 15;
        float a[33];
        #pragma unroll 1
        for (int i = 0; i < 33; ++i) {
            int p = m * 33 + i;
            float acc = sp_b[p];
            #pragma unroll
            for (int j = 0; j < 16; ++j) acc += hs[b][j] * sp_w[p * 16 + j];
            a[i] = acc;
        }
        float s = 0.f;
        #pragma unroll
        for (int i = 0; i < 33; ++i) s += fabsf(a[i]);
        float inv = 1.0f / (s + 0.001f);
        #pragma unroll
        for (int c = 0; c < 32; ++c) att[(b * 16 + m) * 32 + c] = a[c] * inv;
    }
}

// ---------------- kernel 3: aggregate weights -> Wagg bf16 [b][tap][oc][ic] --
__global__ void k_agg(const float* __restrict__ cells, const float* __restrict__ att,
                      ush* __restrict__ wagg) {
    __shared__ float at[512];
    int blk = blockIdx.x;                 // 32*64
    int b = blk >> 6, co = blk & 63;
    int t = threadIdx.x;
    for (int i = t; i < 512; i += 256) at[i] = att[b * 512 + i];
    __syncthreads();
    int ci = t & 63, gi = t >> 6;
    float acc[4][9];
    #pragma unroll
    for (int g = 0; g < 4; ++g)
        #pragma unroll
        for (int k = 0; k < 9; ++k) acc[g][k] = 0.f;
    for (int c = 0; c < 32; ++c) {
        float a0 = at[(0 + gi) * 32 + c];
        float a1 = at[(4 + gi) * 32 + c];
        float a2 = at[(8 + gi) * 32 + c];
        float a3 = at[(12 + gi) * 32 + c];
        const float* cp = cells + (size_t)c * 36864 + co * 576 + ci * 9;
        #pragma unroll
        for (int k = 0; k < 9; ++k) {
            float cv = cp[k];
            acc[0][k] += a0 * cv; acc[1][k] += a1 * cv;
            acc[2][k] += a2 * cv; acc[3][k] += a3 * cv;
        }
    }
    #pragma unroll
    for (int g = 0; g < 4; ++g)
        #pragma unroll
        for (int k = 0; k < 9; ++k)
            wagg[((size_t)(b * 9 + k) * 256 + g * 64 + co) * 256 + gi * 64 + ci] = f2bf(acc[g][k]);
}

// ---------------- kernel 4: conv via implicit-GEMM MFMA ----------------
// A = x pixels (M), B = weights (N=oc); wave = 112 px x 64 oc (7 x-frags x 4 w-frags)
// block: (b, 128-oc tile, 4-row tile); 4 waves = 2 px-halves x 2 oc-halves
// x-fragments double-buffered in registers one tap ahead (hide lgkm latency)
__global__ __launch_bounds__(256, 2) void k_conv(const ush* __restrict__ xT,
                                                 const ush* __restrict__ wagg,
                                                 float* __restrict__ out) {
    __shared__ __align__(16) ush xs[2][12288];   // [buf][row6][col64][ic32]

    int tid = threadIdx.x;
    // XCD-grouped: 14 spatial tiles of one (b,octile) land on one XCD
    int wg  = blockIdx.x;                // 896
    int xcd = wg & 7;
    int kk  = wg >> 3;                   // 0..111
    int gq  = kk / 14;                   // 0..7
    int sp  = kk - gq * 14;              // spatial tile 0..13
    int g   = gq * 8 + xcd;              // 0..63
    int b   = g >> 1, octile = g & 1;
    int row0 = sp * 4, oc0 = octile * 128;

    int lane = tid & 63, w = tid >> 6;
    int wm = w >> 1, wn = w & 1;         // wm: oc half (64), wn: px half (112)
    int l15 = lane & 15, s4 = lane >> 4;

    {   // zero both LDS buffers (invalid rows stay zero forever)
        u32x4 z = (u32x4)(0u);
        #pragma unroll
        for (int i = 0; i < 12; ++i) ((u32x4*)xs)[tid + i * 256] = z;
    }

    int prow[7], pq[7];
    #pragma unroll
    for (int j = 0; j < 7; ++j) {
        int px = wn * 112 + j * 16 + l15;
        prow[j] = px / 56;
        pq[j]   = px - prow[j] * 56;
    }

    unsigned vmask = 0;
    #pragma unroll
    for (int k = 0; k < 6; ++k) {
        int grow = row0 - 1 + k;
        if (grow >= 0 && grow < 56) vmask |= 1u << k;
    }

    // weight base: frag mi -> oc = oc0 + wm*64 + mi*16 + l15, ic = s4*8..+8
    const ush* wb = wagg + (size_t)b * 9 * 65536 + (size_t)(oc0 + wm * 64 + l15) * 256 + s4 * 8;
    const ush* xb = xT + (size_t)b * 8 * 56 * 2048 + (size_t)tid * 8;   // per-lane
    ush* lq = &xs[0][0];                 // base; buffer offset added statically

    f32x4 acc[4][7];
    #pragma unroll
    for (int mi = 0; mi < 4; ++mi)
        #pragma unroll
        for (int j = 0; j < 7; ++j) acc[mi][j] = (f32x4)(0.f);

    // weight pipeline: stage = (chunk + tap) & 1 (9 taps/chunk is odd)
    U16B wpa[2][4];
    #pragma unroll
    for (int mi = 0; mi < 4; ++mi) {
        wpa[0][mi].u = *(const u32x4*)(wb + mi * 4096);           // (c0,t0)
        wpa[1][mi].u = *(const u32x4*)(wb + 65536 + mi * 4096);   // (c0,t1)
    }

    __syncthreads();                      // LDS zero visible before DMA

    // prologue: DMA x chunk 0 -> buf 0 (dest = wave-uniform base + lane*16B)
    #pragma unroll
    for (int k = 0; k < 6; ++k)
        if (vmask & (1u << k))
            gl_lds16(xb + (size_t)(row0 - 1 + k) * 2048, lq + k * 2048 + w * 512);
    __syncthreads();

    auto chunk_body = [&](auto parc, int chunk) {
        constexpr int PAR = decltype(parc)::value;    // == chunk & 1
        if (chunk < 7) {   // DMA next chunk into other buffer (drained by barrier)
            #pragma unroll
            for (int k = 0; k < 6; ++k)
                if (vmask & (1u << k))
                    gl_lds16(xb + (size_t)((chunk + 1) * 56 + row0 - 1 + k) * 2048,
                             lq + (PAR ^ 1) * 12288 + k * 2048 + w * 512);
        }
        const ush* xsb = xs[PAR];
        U16B bj[2][7];                    // x-frag ping-pong, indices compile-time
        #pragma unroll
        for (int j = 0; j < 7; ++j) {     // preload tap 0 (dy=0, dx=0)
            int q = pq[j];
            int slot = s4 ^ ((q >> 1) & 3);
            bj[0][j].u = *(const u32x4*)(xsb + (prow[j] * 64 + q) * 32 + slot * 8);
        }
        #pragma unroll
        for (int tap = 0; tap < 9; ++tap) {
            constexpr int TAPMOD = 0;  (void)TAPMOD;
            const int cur = tap & 1;
            if (tap < 8) {   // issue next tap's x-frag ds_reads (consumed next iter)
                const int dy = (tap + 1) / 3, dx = (tap + 1) % 3;
                #pragma unroll
                for (int j = 0; j < 7; ++j) {
                    int q = pq[j] + dx;
                    int slot = s4 ^ ((q >> 1) & 3);
                    bj[cur ^ 1][j].u =
                        *(const u32x4*)(xsb + ((prow[j] + dy) * 64 + q) * 32 + slot * 8);
                }
            }
            // MFMAs for this tap (weights from stage (PAR+tap)&1, compile-time)
            #pragma unroll
            for (int j = 0; j < 7; ++j) {
                acc[0][j] = __builtin_amdgcn_mfma_f32_16x16x32_bf16(
                    bj[cur][j].b, wpa[(PAR + tap) & 1][0].b, acc[0][j], 0, 0, 0);
                acc[1][j] = __builtin_amdgcn_mfma_f32_16x16x32_bf16(
                    bj[cur][j].b, wpa[(PAR + tap) & 1][1].b, acc[1][j], 0, 0, 0);
                acc[2][j] = __builtin_amdgcn_mfma_f32_16x16x32_bf16(
                    bj[cur][j].b, wpa[(PAR + tap) & 1][2].b, acc[2][j], 0, 0, 0);
                acc[3][j] = __builtin_amdgcn_mfma_f32_16x16x32_bf16(
                    bj[cur][j].b, wpa[(PAR + tap) & 1][3].b, acc[3][j], 0, 0, 0);
            }
            {   // refill the just-consumed weight stage with step k+2 (used tap+2)
                int nt = tap + 2, nc = chunk;
                if (nt >= 9) { nt -= 9; ++nc; }
                if (nc < 8) {
                    const ush* wnx = wb + (size_t)nt * 65536 + (size_t)nc * 32;
                    #pragma unroll
                    for (int mi = 0; mi < 4; ++mi)
                        wpa[(PAR + tap) & 1][mi].u = *(const u32x4*)(wnx + mi * 4096);
                }
            }
        }
        __syncthreads();   // drains DMA (vmcnt) + orders buffer swap
    };

    for (int c2 = 0; c2 < 8; c2 += 2) {
        chunk_body(ICx<0>{}, c2);
        chunk_body(ICx<1>{}, c2 + 1);
    }

    // epilogue: D row = px (4 consecutive per lane via s4), col = oc (l15)
    int pxbase = row0 * 56 + wn * 112 + s4 * 4;
    #pragma unroll
    for (int mi = 0; mi < 4; ++mi) {
        int oc = oc0 + wm * 64 + mi * 16 + l15;
        float* o = out + (size_t)(b * 256 + oc) * HWPX + pxbase;
        #pragma unroll
        for (int j = 0; j < 7; ++j)
            *(f32x4*)(o + j * 16) = acc[mi][j];
    }
}

// ---------------- launcher ----------------
extern "C" void kernel_launch(void* const* d_in, const int* in_sizes, int n_in,
                              void* d_out, int out_size, void* d_ws, size_t ws_size,
                              hipStream_t stream) {
    const float* x     = (const float*)d_in[0];
    const float* cells = (const float*)d_in[1];
    const float* fc1_w = (const float*)d_in[2];
    const float* fc1_b = (const float*)d_in[3];
    const float* ln_g  = (const float*)d_in[4];
    const float* ln_b  = (const float*)d_in[5];
    const float* sp_w  = (const float*)d_in[6];
    const float* sp_b  = (const float*)d_in[7];
    float* out = (float*)d_out;

    char* ws = (char*)d_ws;
    ush*   xT     = (ush*)ws;
    float* pooled = (float*)(ws + POOL_OFF);
    float* att    = (float*)(ws + ATT_OFF);
    ush*   wagg   = (ush*)(ws + WAGG_OFF);

    k_halo<<<448, 256, 0, stream>>>((u32x4*)ws, (u32x4*)pooled);
    k_transpose<<<6272, 256, 0, stream>>>(x, xT, pooled);
    k_attn<<<1, 512, 0, stream>>>(pooled, fc1_w, fc1_b, ln_g, ln_b, sp_w, sp_b, att);
    k_agg<<<2048, 256, 0, stream>>>(cells, att, wagg);
    k_conv<<<896, 256, 0, stream>>>(xT, wagg, out);
}